// Round 2
// baseline (618.063 us; speedup 1.0000x reference)
//
#include <hip/hip_runtime.h>
#include <hip/hip_bf16.h>
#include <stdint.h>

// LoRA linear: out = x @ W^T + b + 2*(x@A^T)@B^T, M=8192, N=K=4096, rank 16.
// Strategy: fold adapter into weights (W' = W + 2*B@A, bf16), single bf16 MFMA GEMM.
// R2 (this round): GEMM ported from 128x128/2-barrier (ceiling ~1.0 PF, MfmaUtil 47%)
// to the 256x256 8-phase counted-vmcnt schedule (T3+T4+T5): 8 waves (2Mx4N),
// BK=64, 128 KiB double-buffered LDS, per-phase half-tile prefetch, vmcnt(6)
// drains only at K-tile boundaries. Pre-pass kernels unchanged (isolate the change).
#define MM 8192
#define NN 4096
#define KK 4096
#define RANK 16
#define SCALING 2.0f

typedef __bf16 bf16x8 __attribute__((ext_vector_type(8)));
typedef float  f32x4  __attribute__((ext_vector_type(4)));

__device__ __forceinline__ void async_copy16(const void* g, void* lds) {
    __builtin_amdgcn_global_load_lds(
        (const __attribute__((address_space(1))) void*)g,
        (__attribute__((address_space(3))) void*)lds,
        16, 0, 0);
}

#define CFENCE asm volatile("" ::: "memory")

// ---------------------------------------------------------------- x fp32 -> bf16
#define CONV_BLOCKS 16384   // MM*KK / 8 / 256

__global__ __launch_bounds__(256, 8)
void conv_x_kernel(const float* __restrict__ x, __hip_bfloat16* __restrict__ xb) {
    size_t i = (size_t)blockIdx.x * 256 + threadIdx.x;   // one 8-elem chunk
    const float4* s = (const float4*)x + i * 2;
    float4 a = s[0], b = s[1];
    union { __hip_bfloat16 h[8]; uint4 u; } o;
    o.h[0] = __float2bfloat16(a.x); o.h[1] = __float2bfloat16(a.y);
    o.h[2] = __float2bfloat16(a.z); o.h[3] = __float2bfloat16(a.w);
    o.h[4] = __float2bfloat16(b.x); o.h[5] = __float2bfloat16(b.y);
    o.h[6] = __float2bfloat16(b.z); o.h[7] = __float2bfloat16(b.w);
    *((uint4*)xb + i) = o.u;
}

// ---------------------------------------------------------------- W' = W + 2*B@A -> bf16
#define PREP_BLOCKS 8192    // NN*KK / 8 / 256

__global__ __launch_bounds__(256, 4)
void prep_w_kernel(const float* __restrict__ W,
                   const float* __restrict__ lA,
                   const float* __restrict__ lB,
                   __hip_bfloat16* __restrict__ wb) {
    size_t idx = (size_t)blockIdx.x * 256 + threadIdx.x;
    int o  = (int)(idx >> 9);          // output row (KK/8 = 512 chunks/row)
    int i0 = ((int)idx & 511) << 3;
    const float4* wp = (const float4*)(W + (size_t)o * KK + i0);
    float4 w0 = wp[0], w1 = wp[1];
    const float4* bp = (const float4*)(lB + (size_t)o * RANK);
    float4 bq0 = bp[0], bq1 = bp[1], bq2 = bp[2], bq3 = bp[3];
    float bv[RANK] = { bq0.x, bq0.y, bq0.z, bq0.w,
                       bq1.x, bq1.y, bq1.z, bq1.w,
                       bq2.x, bq2.y, bq2.z, bq2.w,
                       bq3.x, bq3.y, bq3.z, bq3.w };
    float acc[8] = {0,0,0,0,0,0,0,0};
#pragma unroll 4
    for (int r = 0; r < RANK; ++r) {
        float b = bv[r];
        const float4* ap = (const float4*)(lA + (size_t)r * KK + i0);
        float4 a0 = ap[0], a1 = ap[1];
        acc[0] += b * a0.x; acc[1] += b * a0.y;
        acc[2] += b * a0.z; acc[3] += b * a0.w;
        acc[4] += b * a1.x; acc[5] += b * a1.y;
        acc[6] += b * a1.z; acc[7] += b * a1.w;
    }
    float res[8] = { w0.x + SCALING * acc[0], w0.y + SCALING * acc[1],
                     w0.z + SCALING * acc[2], w0.w + SCALING * acc[3],
                     w1.x + SCALING * acc[4], w1.y + SCALING * acc[5],
                     w1.z + SCALING * acc[6], w1.w + SCALING * acc[7] };
    union { __hip_bfloat16 h[8]; uint4 u; } pk;
#pragma unroll
    for (int j = 0; j < 8; ++j) pk.h[j] = __float2bfloat16(res[j]);
    *((uint4*)wb + idx) = pk.u;
}

// ---------------------------------------------------------------- main GEMM (256^2, 8-phase)
// C = A(bf16)@B(bf16)^T + bias. 256x256 tile, BK=64, 512 threads = 8 waves (wm 0..1, wn 0..3),
// per-wave output 128x64 = acc[8][4] of 16x16 frags. LDS [256][64] bf16 per matrix,
// double-buffered (128 KiB). Chunk-XOR swizzle slot = chunk ^ (row&7) on the GLOBAL
// source (global_load_lds dest must be linear wave-uniform base + lane*16).
// Per K-tile: 4 phases = quadrants (0,0)->(0,1)->(1,1)->(1,0); each phase prefetches
// one 16-KiB half-tile of a FUTURE tile into regions whose single LDS read completed
// a phase earlier. vmcnt(6) once per K-tile (2 loads/phase x 3 phases in flight).
#define GBM 256
#define GBN 256
#define GBK 64
#define NT (KK / GBK)     // 64 K-tiles

__device__ __forceinline__ void ldsA4(bf16x8 (&a)[4][2], const __hip_bfloat16* as,
                                      int rowbase, int slot0, int slot1) {
#pragma unroll
    for (int mi = 0; mi < 4; ++mi) {
        const __hip_bfloat16* p = as + (size_t)(rowbase + mi * 16) * 64;
        a[mi][0] = *(const bf16x8*)(p + slot0);
        a[mi][1] = *(const bf16x8*)(p + slot1);
    }
}

__device__ __forceinline__ void ldsB2(bf16x8 (&b)[2][2], const __hip_bfloat16* bs,
                                      int rowbase, int slot0, int slot1) {
#pragma unroll
    for (int ni = 0; ni < 2; ++ni) {
        const __hip_bfloat16* p = bs + (size_t)(rowbase + ni * 16) * 64;
        b[ni][0] = *(const bf16x8*)(p + slot0);
        b[ni][1] = *(const bf16x8*)(p + slot1);
    }
}

__device__ __forceinline__ void mfma_quad(f32x4 (&acc)[8][4], const bf16x8 (&a)[4][2],
                                          const bf16x8 (&b)[2][2], int mg0, int ng0) {
#pragma unroll
    for (int mi = 0; mi < 4; ++mi)
#pragma unroll
        for (int ni = 0; ni < 2; ++ni)
#pragma unroll
            for (int h = 0; h < 2; ++h)
                acc[mg0 + mi][ng0 + ni] = __builtin_amdgcn_mfma_f32_16x16x32_bf16(
                    a[mi][h], b[ni][h], acc[mg0 + mi][ng0 + ni], 0, 0, 0);
}

__global__ __launch_bounds__(512, 2)
void gemm256_kernel(const __hip_bfloat16* __restrict__ A,
                    const __hip_bfloat16* __restrict__ B,
                    const float* __restrict__ bias,
                    float* __restrict__ C) {
    __shared__ __align__(16) __hip_bfloat16 As[2][GBM * GBK];  // 64 KiB
    __shared__ __align__(16) __hip_bfloat16 Bs[2][GBN * GBK];  // 64 KiB

    const int t     = threadIdx.x;
    const int lane  = t & 63;
    const int wave  = t >> 6;          // 0..7
    const int wm    = wave >> 2;       // 0..1 (M half)
    const int wn    = wave & 3;        // 0..3 (N quarter)
    const int row16 = lane & 15;
    const int quad  = lane >> 4;

    // XCD-bijective swizzle (512 blocks, 512 % 8 == 0): each XCD gets 64
    // contiguous tiles = 4 bm-rows x 16 bn -> A-panel reuse within an XCD's L2.
    const int bid = blockIdx.x;
    const int swz = (bid & 7) * 64 + (bid >> 3);
    const int bm  = swz >> 4;          // 0..31
    const int bn  = swz & 15;          // 0..15

    // staging geometry: wave covers 8 rows/sweep, lane -> (row = ssub, slot = lane&7),
    // source chunk = slot ^ (row&7) (row bases are all multiples of 8).
    const int ssub   = lane >> 3;
    const int schunk = ((lane & 7) ^ ssub) * 8;      // element offset in row
    const int awave  = wave * 8;                     // contiguous sweeps (A)
    const int bwave  = (wave & 3) * 8 + (wave >> 2) * 64;  // striped sweeps (B)

    const __hip_bfloat16* gA = A + (size_t)(bm * GBM) * KK;
    const __hip_bfloat16* gB = B + (size_t)(bn * GBN) * KK;

#define STG_A(buf, rb, kt) \
    async_copy16(gA + (size_t)((rb) + awave + ssub) * KK + (kt) + schunk, \
                 (char*)(As[buf]) + ((rb) + awave) * 128)
#define STG_B(buf, rb, kt) \
    async_copy16(gB + (size_t)((rb) + bwave + ssub) * KK + (kt) + schunk, \
                 (char*)(Bs[buf]) + ((rb) + bwave) * 128)

    f32x4 acc[8][4] = {};

    const int slot0 = (quad ^ (row16 & 7)) * 8;      // k-half 0 (chunks 0..3)
    const int slot1 = slot0 ^ 32;                    // k-half 1 (chunks 4..7)

    // ---- prologue: tile 0 fully (8 loads), tile 1 first 6 quarters.
    // Drain to 6 outstanding -> tile 0 resident, tile 1's 6 still in flight.
    STG_A(0, 0, 0);    STG_A(0, 128, 0);    // A-even
    STG_B(0, 0, 0);    STG_B(0, 128, 0);    // B-qn0 stripes
    STG_A(0, 64, 0);   STG_A(0, 192, 0);    // A-odd
    STG_B(0, 32, 0);   STG_B(0, 160, 0);    // B-qn1 stripes
    CFENCE;
    STG_A(1, 0, GBK);  STG_A(1, 128, GBK);
    STG_B(1, 0, GBK);  STG_B(1, 128, GBK);
    STG_A(1, 64, GBK); STG_A(1, 192, GBK);
    asm volatile("s_waitcnt vmcnt(6)" ::: "memory");
    CFENCE; __builtin_amdgcn_s_barrier(); CFENCE;

    for (int tk = 0; tk < NT; ++tk) {
        const int cur = tk & 1, nxt = cur ^ 1;
        const __hip_bfloat16* as = As[cur];
        const __hip_bfloat16* bs = Bs[cur];
        const int kt1 = (tk + 1) * GBK;
        const int kt2 = (tk + 2) * GBK;
        const bool s0  = tk < NT - 1;   // tile t+1 tail stage valid
        const bool s12 = tk < NT - 2;   // tile t+2 stages valid

        bf16x8 af[4][2], b0[2][2], b1[2][2];

        // -------- phase 0: quadrant (qm0, qn0). Reads A rows wm*128+[0,64) + B qn0.
        // Stage: tile t+1's B-qn1 tail into other buf (dead since p1 of tile t-1).
        ldsA4(af, as, wm * 128 + row16, slot0, slot1);
        ldsB2(b0, bs, wn * 64 + row16, slot0, slot1);
        if (s0) { STG_B(nxt, 32, kt1); STG_B(nxt, 160, kt1); }
        CFENCE; __builtin_amdgcn_s_barrier();
        asm volatile("s_waitcnt lgkmcnt(0)" ::: "memory");
        __builtin_amdgcn_s_setprio(1);
        mfma_quad(acc, af, b0, 0, 0);
        __builtin_amdgcn_s_setprio(0);
        CFENCE; __builtin_amdgcn_s_barrier(); CFENCE;

        // -------- phase 1: quadrant (qm0, qn1). Reads B qn1; A frags reused.
        // Stage: tile t+2 A-even into cur buf (dead after p0).
        ldsB2(b1, bs, wn * 64 + 32 + row16, slot0, slot1);
        if (s12) { STG_A(cur, 0, kt2); STG_A(cur, 128, kt2); }
        CFENCE; __builtin_amdgcn_s_barrier();
        asm volatile("s_waitcnt lgkmcnt(0)" ::: "memory");
        __builtin_amdgcn_s_setprio(1);
        mfma_quad(acc, af, b1, 0, 2);
        __builtin_amdgcn_s_setprio(0);
        CFENCE; __builtin_amdgcn_s_barrier(); CFENCE;

        // -------- phase 2: quadrant (qm1, qn1). Reads A rows wm*128+[64,128); b1 reused.
        // Stage: tile t+2 B-qn0 stripes (dead after p0).
        ldsA4(af, as, wm * 128 + 64 + row16, slot0, slot1);
        if (s12) { STG_B(cur, 0, kt2); STG_B(cur, 128, kt2); }
        CFENCE; __builtin_amdgcn_s_barrier();
        asm volatile("s_waitcnt lgkmcnt(0)" ::: "memory");
        __builtin_amdgcn_s_setprio(1);
        mfma_quad(acc, af, b1, 4, 2);
        __builtin_amdgcn_s_setprio(0);
        CFENCE; __builtin_amdgcn_s_barrier(); CFENCE;

        // -------- phase 3: quadrant (qm1, qn0). No LDS reads (af new, b0 held).
        // Stage: tile t+2 A-odd (dead after p2). K-tile drain: vmcnt(6) keeps the
        // 6 newest (tile t+2 q1-6) in flight; completes tile t+1 -> resident.
        if (s12) { STG_A(cur, 64, kt2); STG_A(cur, 192, kt2); }
        CFENCE; __builtin_amdgcn_s_barrier();
        asm volatile("s_waitcnt lgkmcnt(0)" ::: "memory");
        __builtin_amdgcn_s_setprio(1);
        mfma_quad(acc, af, b0, 4, 0);
        __builtin_amdgcn_s_setprio(0);
        if (s12) asm volatile("s_waitcnt vmcnt(6)" ::: "memory");
        else     asm volatile("s_waitcnt vmcnt(0)" ::: "memory");
        CFENCE; __builtin_amdgcn_s_barrier(); CFENCE;
    }
#undef STG_A
#undef STG_B

    // epilogue: C/D layout col=lane&15, row=quad*4+reg (verified in 128^2 kernel)
    const int colBase = bn * GBN + wn * 64;
    const int rowBase = bm * GBM + wm * 128;
#pragma unroll
    for (int ng = 0; ng < 4; ++ng) {
        int col = colBase + ng * 16 + row16;
        float bv = bias[col];
#pragma unroll
        for (int mg = 0; mg < 8; ++mg) {
            int r0 = rowBase + mg * 16 + quad * 4;
#pragma unroll
            for (int i = 0; i < 4; ++i)
                C[(size_t)(r0 + i) * NN + col] = acc[mg][ng][i] + bv;
        }
    }
}

// ---------------------------------------------------------------- fallback (ws too small)
__global__ void naive_base_kernel(const float* __restrict__ x,
                                  const float* __restrict__ W,
                                  const float* __restrict__ b,
                                  float* __restrict__ out) {
    size_t idx = (size_t)blockIdx.x * 256 + threadIdx.x;
    int m = (int)(idx / NN), n = (int)(idx % NN);
    const float* xr = x + (size_t)m * KK;
    const float* wr = W + (size_t)n * KK;
    float s = 0.f;
    for (int k = 0; k < KK; ++k) s += xr[k] * wr[k];
    out[idx] = s + b[n];
}

__global__ void naive_adapter_kernel(const float* __restrict__ x,
                                     const float* __restrict__ lA,
                                     const float* __restrict__ lB,
                                     float* __restrict__ out) {
    int m = blockIdx.x;
    __shared__ float xa[RANK];
    __shared__ float red[256];
    const float* xr = x + (size_t)m * KK;
    for (int r = 0; r < RANK; ++r) {
        float p = 0.f;
        for (int k = threadIdx.x; k < KK; k += 256) p += xr[k] * lA[(size_t)r * KK + k];
        red[threadIdx.x] = p;
        __syncthreads();
        for (int s = 128; s > 0; s >>= 1) {
            if (threadIdx.x < s) red[threadIdx.x] += red[threadIdx.x + s];
            __syncthreads();
        }
        if (threadIdx.x == 0) xa[r] = red[0];
        __syncthreads();
    }
    for (int n = threadIdx.x; n < NN; n += 256) {
        float adj = 0.f;
#pragma unroll
        for (int r = 0; r < RANK; ++r) adj += xa[r] * lB[n * RANK + r];
        out[(size_t)m * NN + n] += SCALING * adj;
    }
}

// ---------------------------------------------------------------- launch
extern "C" void kernel_launch(void* const* d_in, const int* in_sizes, int n_in,
                              void* d_out, int out_size, void* d_ws, size_t ws_size,
                              hipStream_t stream) {
    const float* x  = (const float*)d_in[0];
    const float* W  = (const float*)d_in[1];
    const float* b  = (const float*)d_in[2];
    const float* lA = (const float*)d_in[3];
    const float* lB = (const float*)d_in[4];
    float* out = (float*)d_out;

    size_t need = (size_t)MM * KK * 2 + (size_t)NN * KK * 2;  // ~96 MiB
    if (ws_size >= need) {
        __hip_bfloat16* xb = (__hip_bfloat16*)d_ws;
        __hip_bfloat16* wb = xb + (size_t)MM * KK;
        conv_x_kernel<<<CONV_BLOCKS, 256, 0, stream>>>(x, xb);
        prep_w_kernel<<<PREP_BLOCKS, 256, 0, stream>>>(W, lA, lB, wb);
        gemm256_kernel<<<(MM / GBM) * (NN / GBN), 512, 0, stream>>>(xb, wb, b, out);
    } else {
        naive_base_kernel<<<(size_t)MM * NN / 256, 256, 0, stream>>>(x, W, b, out);
        naive_adapter_kernel<<<MM, 256, 0, stream>>>(x, lA, lB, out);
    }
}

// Round 3
// 589.689 us; speedup vs baseline: 1.0481x; 1.0481x over previous
//
#include <hip/hip_runtime.h>
#include <hip/hip_bf16.h>
#include <stdint.h>

// LoRA linear: out = x @ W^T + b + 2*(x@A^T)@B^T, M=8192, N=K=4096, rank 16.
// Strategy: fold adapter into weights (W' = W + 2*B@A, bf16), single bf16 MFMA GEMM.
// R3 (this round): 8-phase 256^2 GEMM v2. v1 (356us, MfmaUtil 32%) was strangled by
// compiler-scheduling fences (m141 failure mode) + dependent back-to-back MFMA pairs.
// v2: minimal fencing (memory clobber only on vmcnt drains), h-outer MFMA order
// (dependent reuse distance 8), lgkmcnt(8) pre-drain on the 12-read phase, unroll 2.
#define MM 8192
#define NN 4096
#define KK 4096
#define RANK 16
#define SCALING 2.0f

typedef __bf16 bf16x8 __attribute__((ext_vector_type(8)));
typedef float  f32x4  __attribute__((ext_vector_type(4)));

__device__ __forceinline__ void async_copy16(const void* g, void* lds) {
    __builtin_amdgcn_global_load_lds(
        (const __attribute__((address_space(1))) void*)g,
        (__attribute__((address_space(3))) void*)lds,
        16, 0, 0);
}

// ---------------------------------------------------------------- x fp32 -> bf16
#define CONV_BLOCKS 16384   // MM*KK / 8 / 256

__global__ __launch_bounds__(256, 8)
void conv_x_kernel(const float* __restrict__ x, __hip_bfloat16* __restrict__ xb) {
    size_t i = (size_t)blockIdx.x * 256 + threadIdx.x;   // one 8-elem chunk
    const float4* s = (const float4*)x + i * 2;
    float4 a = s[0], b = s[1];
    union { __hip_bfloat16 h[8]; uint4 u; } o;
    o.h[0] = __float2bfloat16(a.x); o.h[1] = __float2bfloat16(a.y);
    o.h[2] = __float2bfloat16(a.z); o.h[3] = __float2bfloat16(a.w);
    o.h[4] = __float2bfloat16(b.x); o.h[5] = __float2bfloat16(b.y);
    o.h[6] = __float2bfloat16(b.z); o.h[7] = __float2bfloat16(b.w);
    *((uint4*)xb + i) = o.u;
}

// ---------------------------------------------------------------- W' = W + 2*B@A -> bf16
#define PREP_BLOCKS 8192    // NN*KK / 8 / 256

__global__ __launch_bounds__(256, 4)
void prep_w_kernel(const float* __restrict__ W,
                   const float* __restrict__ lA,
                   const float* __restrict__ lB,
                   __hip_bfloat16* __restrict__ wb) {
    size_t idx = (size_t)blockIdx.x * 256 + threadIdx.x;
    int o  = (int)(idx >> 9);          // output row (KK/8 = 512 chunks/row)
    int i0 = ((int)idx & 511) << 3;
    const float4* wp = (const float4*)(W + (size_t)o * KK + i0);
    float4 w0 = wp[0], w1 = wp[1];
    const float4* bp = (const float4*)(lB + (size_t)o * RANK);
    float4 bq0 = bp[0], bq1 = bp[1], bq2 = bp[2], bq3 = bp[3];
    float bv[RANK] = { bq0.x, bq0.y, bq0.z, bq0.w,
                       bq1.x, bq1.y, bq1.z, bq1.w,
                       bq2.x, bq2.y, bq2.z, bq2.w,
                       bq3.x, bq3.y, bq3.z, bq3.w };
    float acc[8] = {0,0,0,0,0,0,0,0};
#pragma unroll 4
    for (int r = 0; r < RANK; ++r) {
        float b = bv[r];
        const float4* ap = (const float4*)(lA + (size_t)r * KK + i0);
        float4 a0 = ap[0], a1 = ap[1];
        acc[0] += b * a0.x; acc[1] += b * a0.y;
        acc[2] += b * a0.z; acc[3] += b * a0.w;
        acc[4] += b * a1.x; acc[5] += b * a1.y;
        acc[6] += b * a1.z; acc[7] += b * a1.w;
    }
    float res[8] = { w0.x + SCALING * acc[0], w0.y + SCALING * acc[1],
                     w0.z + SCALING * acc[2], w0.w + SCALING * acc[3],
                     w1.x + SCALING * acc[4], w1.y + SCALING * acc[5],
                     w1.z + SCALING * acc[6], w1.w + SCALING * acc[7] };
    union { __hip_bfloat16 h[8]; uint4 u; } pk;
#pragma unroll
    for (int j = 0; j < 8; ++j) pk.h[j] = __float2bfloat16(res[j]);
    *((uint4*)wb + idx) = pk.u;
}

// ---------------------------------------------------------------- main GEMM (256^2, 8-phase)
// C = A(bf16)@B(bf16)^T + bias. 256x256 tile, BK=64, 512 threads = 8 waves (wm 0..1, wn 0..3),
// per-wave output 128x64 = acc[8][4] of 16x16 frags. LDS [256][64] bf16 per matrix,
// double-buffered (128 KiB). Chunk-XOR swizzle slot = chunk ^ (row&7) on the GLOBAL
// source (global_load_lds dest must be linear wave-uniform base + lane*16).
// Per K-tile: 4 phases = quadrants (0,0)->(0,1)->(1,1)->(1,0); each phase prefetches
// one-quarter tile of a FUTURE tile into regions whose LDS read completed a phase
// earlier. vmcnt(6) once per K-tile. Hazard spacing: every stage targets a region
// last read >= 1 phase + lgkmcnt(0) + barrier before the stage issues; staged data
// is first read only after the next vmcnt drain + barrier.
#define GBM 256
#define GBN 256
#define GBK 64
#define NT (KK / GBK)     // 64 K-tiles

__device__ __forceinline__ void ldsA4(bf16x8 (&a)[4][2], const __hip_bfloat16* as,
                                      int rowbase, int slot0, int slot1) {
#pragma unroll
    for (int mi = 0; mi < 4; ++mi) {
        const __hip_bfloat16* p = as + (size_t)(rowbase + mi * 16) * 64;
        a[mi][0] = *(const bf16x8*)(p + slot0);
        a[mi][1] = *(const bf16x8*)(p + slot1);
    }
}

__device__ __forceinline__ void ldsB2(bf16x8 (&b)[2][2], const __hip_bfloat16* bs,
                                      int rowbase, int slot0, int slot1) {
#pragma unroll
    for (int ni = 0; ni < 2; ++ni) {
        const __hip_bfloat16* p = bs + (size_t)(rowbase + ni * 16) * 64;
        b[ni][0] = *(const bf16x8*)(p + slot0);
        b[ni][1] = *(const bf16x8*)(p + slot1);
    }
}

// h-outer: all 8 acc cells at k-half 0, then all 8 at k-half 1.
// Same-cell dependent MFMAs are 8 apart (~38 cyc) -> no pipe stall.
__device__ __forceinline__ void mfma_quad(f32x4 (&acc)[8][4], const bf16x8 (&a)[4][2],
                                          const bf16x8 (&b)[2][2], int mg0, int ng0) {
#pragma unroll
    for (int h = 0; h < 2; ++h)
#pragma unroll
        for (int mi = 0; mi < 4; ++mi)
#pragma unroll
            for (int ni = 0; ni < 2; ++ni)
                acc[mg0 + mi][ng0 + ni] = __builtin_amdgcn_mfma_f32_16x16x32_bf16(
                    a[mi][h], b[ni][h], acc[mg0 + mi][ng0 + ni], 0, 0, 0);
}

__global__ __launch_bounds__(512, 2)
void gemm256_kernel(const __hip_bfloat16* __restrict__ A,
                    const __hip_bfloat16* __restrict__ B,
                    const float* __restrict__ bias,
                    float* __restrict__ C) {
    __shared__ __align__(16) __hip_bfloat16 As[2][GBM * GBK];  // 64 KiB
    __shared__ __align__(16) __hip_bfloat16 Bs[2][GBN * GBK];  // 64 KiB

    const int t     = threadIdx.x;
    const int lane  = t & 63;
    const int wave  = t >> 6;          // 0..7
    const int wm    = wave >> 2;       // 0..1 (M half)
    const int wn    = wave & 3;        // 0..3 (N quarter)
    const int row16 = lane & 15;
    const int quad  = lane >> 4;

    // XCD-bijective swizzle (512 blocks, 512 % 8 == 0): each XCD gets 64
    // contiguous tiles = 4 bm-rows x 16 bn -> A-panel reuse within an XCD's L2.
    const int bid = blockIdx.x;
    const int swz = (bid & 7) * 64 + (bid >> 3);
    const int bm  = swz >> 4;          // 0..31
    const int bn  = swz & 15;          // 0..15

    // staging geometry: wave covers 8 rows/sweep, lane -> (row = ssub, slot = lane&7),
    // source chunk = slot ^ (row&7) (row bases are all multiples of 8).
    const int ssub   = lane >> 3;
    const int schunk = ((lane & 7) ^ ssub) * 8;      // element offset in row
    const int awave  = wave * 8;                     // contiguous sweeps (A)
    const int bwave  = (wave & 3) * 8 + (wave >> 2) * 64;  // striped sweeps (B)

    const __hip_bfloat16* gA = A + (size_t)(bm * GBM) * KK;
    const __hip_bfloat16* gB = B + (size_t)(bn * GBN) * KK;

#define STG_A(buf, rb, kt) \
    async_copy16(gA + (size_t)((rb) + awave + ssub) * KK + (kt) + schunk, \
                 (char*)(As[buf]) + ((rb) + awave) * 128)
#define STG_B(buf, rb, kt) \
    async_copy16(gB + (size_t)((rb) + bwave + ssub) * KK + (kt) + schunk, \
                 (char*)(Bs[buf]) + ((rb) + bwave) * 128)

    f32x4 acc[8][4] = {};

    const int slot0 = (quad ^ (row16 & 7)) * 8;      // k-half 0 (chunks 0..3)
    const int slot1 = slot0 ^ 32;                    // k-half 1 (chunks 4..7)

    // ---- prologue: tile 0 fully (8 loads), tile 1 first 6 quarters.
    // Drain to 6 outstanding -> tile 0 resident, tile 1's 6 still in flight.
    STG_A(0, 0, 0);    STG_A(0, 128, 0);    // A-even
    STG_B(0, 0, 0);    STG_B(0, 128, 0);    // B-qn0 stripes
    STG_A(0, 64, 0);   STG_A(0, 192, 0);    // A-odd
    STG_B(0, 32, 0);   STG_B(0, 160, 0);    // B-qn1 stripes
    STG_A(1, 0, GBK);  STG_A(1, 128, GBK);
    STG_B(1, 0, GBK);  STG_B(1, 128, GBK);
    STG_A(1, 64, GBK); STG_A(1, 192, GBK);
    asm volatile("s_waitcnt vmcnt(6)" ::: "memory");
    __builtin_amdgcn_s_barrier();

#pragma unroll 2
    for (int tk = 0; tk < NT; ++tk) {
        const int cur = tk & 1, nxt = cur ^ 1;
        const __hip_bfloat16* as = As[cur];
        const __hip_bfloat16* bs = Bs[cur];
        const int kt1 = (tk + 1) * GBK;
        const int kt2 = (tk + 2) * GBK;
        const bool s0  = tk < NT - 1;   // tile t+1 tail stage valid
        const bool s12 = tk < NT - 2;   // tile t+2 stages valid

        bf16x8 af[4][2], b0[2][2], b1[2][2];

        // -------- phase 0: quadrant (qm0, qn0). Reads A rows wm*128+[0,64) + B qn0 (12 reads).
        // Stage: tile t+1's B-qn1 tail into other buf (dead since p1 of tile t-1).
        ldsA4(af, as, wm * 128 + row16, slot0, slot1);
        ldsB2(b0, bs, wn * 64 + row16, slot0, slot1);
        if (s0) { STG_B(nxt, 32, kt1); STG_B(nxt, 160, kt1); }
        asm volatile("s_waitcnt lgkmcnt(8)");
        __builtin_amdgcn_s_barrier();
        asm volatile("s_waitcnt lgkmcnt(0)");
        __builtin_amdgcn_s_setprio(1);
        mfma_quad(acc, af, b0, 0, 0);
        __builtin_amdgcn_s_setprio(0);
        __builtin_amdgcn_s_barrier();

        // -------- phase 1: quadrant (qm0, qn1). Reads B qn1 (4); A frags reused.
        // Stage: tile t+2 A-even into cur buf (dead after p0).
        ldsB2(b1, bs, wn * 64 + 32 + row16, slot0, slot1);
        if (s12) { STG_A(cur, 0, kt2); STG_A(cur, 128, kt2); }
        __builtin_amdgcn_s_barrier();
        asm volatile("s_waitcnt lgkmcnt(0)");
        __builtin_amdgcn_s_setprio(1);
        mfma_quad(acc, af, b1, 0, 2);
        __builtin_amdgcn_s_setprio(0);
        __builtin_amdgcn_s_barrier();

        // -------- phase 2: quadrant (qm1, qn1). Reads A rows wm*128+[64,128) (8); b1 reused.
        // Stage: tile t+2 B-qn0 stripes (dead after p0).
        ldsA4(af, as, wm * 128 + 64 + row16, slot0, slot1);
        if (s12) { STG_B(cur, 0, kt2); STG_B(cur, 128, kt2); }
        __builtin_amdgcn_s_barrier();
        asm volatile("s_waitcnt lgkmcnt(0)");
        __builtin_amdgcn_s_setprio(1);
        mfma_quad(acc, af, b1, 4, 2);
        __builtin_amdgcn_s_setprio(0);
        __builtin_amdgcn_s_barrier();

        // -------- phase 3: quadrant (qm1, qn0). No LDS reads (af new, b0 held).
        // Stage: tile t+2 A-odd (dead after p2). K-tile drain: vmcnt(6) keeps the
        // 6 newest (tile t+2 q1-6) in flight; completes tile t+1 -> resident.
        if (s12) { STG_A(cur, 64, kt2); STG_A(cur, 192, kt2); }
        __builtin_amdgcn_s_barrier();
        __builtin_amdgcn_s_setprio(1);
        mfma_quad(acc, af, b0, 4, 0);
        __builtin_amdgcn_s_setprio(0);
        if (s12) asm volatile("s_waitcnt vmcnt(6)" ::: "memory");
        else     asm volatile("s_waitcnt vmcnt(0)" ::: "memory");
        __builtin_amdgcn_s_barrier();
    }
#undef STG_A
#undef STG_B

    // epilogue: C/D layout col=lane&15, row=quad*4+reg (verified in 128^2 kernel)
    const int colBase = bn * GBN + wn * 64;
    const int rowBase = bm * GBM + wm * 128;
#pragma unroll
    for (int ng = 0; ng < 4; ++ng) {
        int col = colBase + ng * 16 + row16;
        float bv = bias[col];
#pragma unroll
        for (int mg = 0; mg < 8; ++mg) {
            int r0 = rowBase + mg * 16 + quad * 4;
#pragma unroll
            for (int i = 0; i < 4; ++i)
                C[(size_t)(r0 + i) * NN + col] = acc[mg][ng][i] + bv;
        }
    }
}

// ---------------------------------------------------------------- fallback (ws too small)
__global__ void naive_base_kernel(const float* __restrict__ x,
                                  const float* __restrict__ W,
                                  const float* __restrict__ b,
                                  float* __restrict__ out) {
    size_t idx = (size_t)blockIdx.x * 256 + threadIdx.x;
    int m = (int)(idx / NN), n = (int)(idx % NN);
    const float* xr = x + (size_t)m * KK;
    const float* wr = W + (size_t)n * KK;
    float s = 0.f;
    for (int k = 0; k < KK; ++k) s += xr[k] * wr[k];
    out[idx] = s + b[n];
}

__global__ void naive_adapter_kernel(const float* __restrict__ x,
                                     const float* __restrict__ lA,
                                     const float* __restrict__ lB,
                                     float* __restrict__ out) {
    int m = blockIdx.x;
    __shared__ float xa[RANK];
    __shared__ float red[256];
    const float* xr = x + (size_t)m * KK;
    for (int r = 0; r < RANK; ++r) {
        float p = 0.f;
        for (int k = threadIdx.x; k < KK; k += 256) p += xr[k] * lA[(size_t)r * KK + k];
        red[threadIdx.x] = p;
        __syncthreads();
        for (int s = 128; s > 0; s >>= 1) {
            if (threadIdx.x < s) red[threadIdx.x] += red[threadIdx.x + s];
            __syncthreads();
        }
        if (threadIdx.x == 0) xa[r] = red[0];
        __syncthreads();
    }
    for (int n = threadIdx.x; n < NN; n += 256) {
        float adj = 0.f;
#pragma unroll
        for (int r = 0; r < RANK; ++r) adj += xa[r] * lB[n * RANK + r];
        out[(size_t)m * NN + n] += SCALING * adj;
    }
}

// ---------------------------------------------------------------- launch
extern "C" void kernel_launch(void* const* d_in, const int* in_sizes, int n_in,
                              void* d_out, int out_size, void* d_ws, size_t ws_size,
                              hipStream_t stream) {
    const float* x  = (const float*)d_in[0];
    const float* W  = (const float*)d_in[1];
    const float* b  = (const float*)d_in[2];
    const float* lA = (const float*)d_in[3];
    const float* lB = (const float*)d_in[4];
    float* out = (float*)d_out;

    size_t need = (size_t)MM * KK * 2 + (size_t)NN * KK * 2;  // ~96 MiB
    if (ws_size >= need) {
        __hip_bfloat16* xb = (__hip_bfloat16*)d_ws;
        __hip_bfloat16* wb = xb + (size_t)MM * KK;
        conv_x_kernel<<<CONV_BLOCKS, 256, 0, stream>>>(x, xb);
        prep_w_kernel<<<PREP_BLOCKS, 256, 0, stream>>>(W, lA, lB, wb);
        gemm256_kernel<<<(MM / GBM) * (NN / GBN), 512, 0, stream>>>(xb, wb, b, out);
    } else {
        naive_base_kernel<<<(size_t)MM * NN / 256, 256, 0, stream>>>(x, W, b, out);
        naive_adapter_kernel<<<MM, 256, 0, stream>>>(x, lA, lB, out);
    }
}